// Round 4
// baseline (665.159 us; speedup 1.0000x reference)
//
#include <hip/hip_runtime.h>
#include <cstddef>
#include <cstdint>

// B=16, TQ=TP=DQ=DP=1024.
//   pW = p @ W ; S' = q @ pW^T (=S^T) ; row-softmax stats on S' ;
//   Ws[p][q] = exp(S'[q][p]-m[q])*rl[q] (transposed exp pass) ; out = Ws @ qT^T
// GEMMs: bf16x3 split MFMA (hh+lh+hl), fragment-linear conflict-free LDS.
//
// Workspace (128.13 MB):
//  R0 [0,64MB):  pWh|pWl (g1->g2'), then Wsh|Wsl (k5->g4)
//  R1 [64,128MB): WTh|WTl (4MB head, conv_w->g1) ; S' f32 (g2'->k5) ;
//                 then qTh|qTl (conv_qt->g4)
//  [128MB,+128KB): m, rl stats

namespace {

using u16 = unsigned short;
using frag  = __attribute__((ext_vector_type(8))) short;  // 8 bf16 = 4 VGPR
using f32x4 = __attribute__((ext_vector_type(4))) float;

constexpr int kB = 16;
constexpr int kT = 1024;
constexpr int kD = 1024;
constexpr int BM = 128, BN = 128, BK = 32;
constexpr int KSTEPS = kD / BK;

union FragU { frag v; u16 u[8]; };

__device__ __forceinline__ u16 f2bf(float x) {  // RNE f32->bf16
  uint32_t u = __float_as_uint(x);
  return (u16)((u + 0x7FFFu + ((u >> 16) & 1u)) >> 16);
}
__device__ __forceinline__ float bf2f(u16 h) {
  return __uint_as_float(((uint32_t)h) << 16);
}

#define AS1(p) (const __attribute__((address_space(1))) void*)(p)
#define AS3(p) (__attribute__((address_space(3))) void*)(p)

__device__ __forceinline__ void gl_lds16(const u16* g, u16* l) {
  __builtin_amdgcn_global_load_lds(AS1(g), AS3(l), 16, 0, 0);
}

// ---------------------------------------------------------------------------
// Fragment-linear tile: [8 groups][64 slots][8 u16].
// slot(g, lane) holds src[row0 + g*16 + (lane&15)][k0 + (lane>>4)*8 .. +7].
// MFMA fragment read for group g: byte base + g*1024 + lane*16  (linear).
// ---------------------------------------------------------------------------

// Stage a pre-split bf16 operand (row-major, stride 1024 u16) via glds.
// Wave w stages groups 2w, 2w+1 (LDS dest linear; permutation in global addr).
__device__ __forceinline__ void stage_frag_glds(const u16* __restrict__ src,
                                                u16* lds, int row0, int k0, int tid) {
  const int w = tid >> 6, l = tid & 63;
  const int rl = l & 15;
  const int kc = (l >> 4) * 8;
#pragma unroll
  for (int i = 0; i < 2; ++i) {
    const int g = w * 2 + i;
    gl_lds16(src + (size_t)(row0 + g * 16 + rl) * 1024 + k0 + kc, lds + g * 512);
  }
}

// Reg-stage an f32 operand: thread t owns slots t and t+256.
__device__ __forceinline__ void load_f32_slots(const float* __restrict__ src,
                                               int row0, int k0, int tid, float4* out) {
#pragma unroll
  for (int i = 0; i < 2; ++i) {
    const int s = tid + i * 256;
    const int row = (s >> 6) * 16 + (s & 15);
    const int kc = ((s >> 4) & 3) * 8;
    const float4* g = (const float4*)(src + (size_t)(row0 + row) * 1024 + k0 + kc);
    out[i * 2 + 0] = g[0];
    out[i * 2 + 1] = g[1];
  }
}

__device__ __forceinline__ void write_split_frag(const float4* v, u16* ldsHi,
                                                 u16* ldsLo, int tid) {
#pragma unroll
  for (int i = 0; i < 2; ++i) {
    const int s = tid + i * 256;
    const float vv[8] = {v[2*i].x, v[2*i].y, v[2*i].z, v[2*i].w,
                         v[2*i+1].x, v[2*i+1].y, v[2*i+1].z, v[2*i+1].w};
    FragU h, lo;
#pragma unroll
    for (int j = 0; j < 8; ++j) {
      const u16 hh = f2bf(vv[j]);
      h.u[j] = hh;
      lo.u[j] = f2bf(vv[j] - bf2f(hh));
    }
    *(frag*)(ldsHi + s * 8) = h.v;   // linear: thread-consecutive 16B slots
    *(frag*)(ldsLo + s * 8) = lo.v;
  }
}

// 3-term MFMA over one K-step (BK=32 = one mfma-K).
__device__ __forceinline__ void compute_step(const u16* AhS, const u16* AlS,
                                             const u16* BhS, const u16* BlS,
                                             f32x4 acc[4][4], int lane, int wr, int wc) {
  const int lo16 = lane * 8;  // u16 offset: lane*16B
  frag ah[4], al[4];
#pragma unroll
  for (int m = 0; m < 4; ++m) {
    ah[m] = *(const frag*)(AhS + (wr * 4 + m) * 512 + lo16);
    al[m] = *(const frag*)(AlS + (wr * 4 + m) * 512 + lo16);
  }
#pragma unroll
  for (int n = 0; n < 4; ++n) {
    const frag bh = *(const frag*)(BhS + (wc * 4 + n) * 512 + lo16);
    const frag bl = *(const frag*)(BlS + (wc * 4 + n) * 512 + lo16);
#pragma unroll
    for (int m = 0; m < 4; ++m) {
      acc[m][n] = __builtin_amdgcn_mfma_f32_16x16x32_bf16(ah[m], bh, acc[m][n], 0, 0, 0);
      acc[m][n] = __builtin_amdgcn_mfma_f32_16x16x32_bf16(al[m], bh, acc[m][n], 0, 0, 0);
      acc[m][n] = __builtin_amdgcn_mfma_f32_16x16x32_bf16(ah[m], bl, acc[m][n], 0, 0, 0);
    }
  }
}

// C/D layout (verified m89/m91): col = lane&15, row = (lane>>4)*4 + reg.
__device__ __forceinline__ void epilogue_f32(float* __restrict__ dst, f32x4 acc[4][4],
                                             int row0, int col0, int lane, int wr, int wc) {
#pragma unroll
  for (int m = 0; m < 4; ++m)
#pragma unroll
    for (int n = 0; n < 4; ++n) {
      const int col = col0 + wc * 64 + n * 16 + (lane & 15);
      const int rb  = row0 + wr * 64 + m * 16 + ((lane >> 4) << 2);
#pragma unroll
      for (int j = 0; j < 4; ++j)
        dst[(size_t)(rb + j) * 1024 + col] = acc[m][n][j];
    }
}

// ---------------------------------------------------------------------------
// g1: pW = p @ WT^T.  A = p (f32 reg-split), B = WT hi/lo (glds).
// Writes pW split hi/lo bf16, row-major [16384][1024].
// ---------------------------------------------------------------------------
__global__ __launch_bounds__(256) void g1_pw(const float* __restrict__ P,
                                             const u16* __restrict__ WTh,
                                             const u16* __restrict__ WTl,
                                             u16* __restrict__ pWh,
                                             u16* __restrict__ pWl) {
  __shared__ __align__(16) u16 AhS[4096], AlS[4096], BhS[4096], BlS[4096];
  const int tid = threadIdx.x, lane = tid & 63;
  const int wid = tid >> 6, wr = wid >> 1, wc = wid & 1;
  const int m0 = blockIdx.y * BM, n0 = blockIdx.x * BN;

  f32x4 acc[4][4];
#pragma unroll
  for (int m = 0; m < 4; ++m)
#pragma unroll
    for (int n = 0; n < 4; ++n) acc[m][n] = (f32x4){0.f, 0.f, 0.f, 0.f};

  float4 areg[4];
  load_f32_slots(P, m0, 0, tid, areg);
#pragma unroll 1
  for (int ks = 0; ks < KSTEPS; ++ks) {
    const int k0 = ks * BK;
    __syncthreads();
    stage_frag_glds(WTh, BhS, n0, k0, tid);
    stage_frag_glds(WTl, BlS, n0, k0, tid);
    write_split_frag(areg, AhS, AlS, tid);
    if (ks + 1 < KSTEPS) load_f32_slots(P, m0, k0 + BK, tid, areg);
    __syncthreads();
    compute_step(AhS, AlS, BhS, BlS, acc, lane, wr, wc);
  }

#pragma unroll
  for (int m = 0; m < 4; ++m)
#pragma unroll
    for (int n = 0; n < 4; ++n) {
      const int col = n0 + wc * 64 + n * 16 + (lane & 15);
      const int rb  = m0 + wr * 64 + m * 16 + ((lane >> 4) << 2);
#pragma unroll
      for (int j = 0; j < 4; ++j) {
        const float x = acc[m][n][j];
        const u16 h = f2bf(x);
        pWh[(size_t)(rb + j) * 1024 + col] = h;
        pWl[(size_t)(rb + j) * 1024 + col] = f2bf(x - bf2f(h));
      }
    }
}

// ---------------------------------------------------------------------------
// g2': S'[b][q][p] = q[b] @ pW[b]^T.  A = q (f32 reg-split), B = pW hi/lo (glds).
// ---------------------------------------------------------------------------
__global__ __launch_bounds__(256) void g2_scoresT(const float* __restrict__ Q,
                                                  const u16* __restrict__ pWh,
                                                  const u16* __restrict__ pWl,
                                                  float* __restrict__ Sp) {
  __shared__ __align__(16) u16 AhS[4096], AlS[4096], BhS[4096], BlS[4096];
  const int tid = threadIdx.x, lane = tid & 63;
  const int wid = tid >> 6, wr = wid >> 1, wc = wid & 1;
  const int b = blockIdx.z;
  const int m0 = blockIdx.y * BM, n0 = blockIdx.x * BN;  // m = q rows, n = p cols
  const float* Qb = Q + (size_t)b * kT * kD;
  const int rowB0 = b * kT + n0;                         // pW flat [16384][1024]
  float* Sb = Sp + (size_t)b * kT * kT;

  f32x4 acc[4][4];
#pragma unroll
  for (int m = 0; m < 4; ++m)
#pragma unroll
    for (int n = 0; n < 4; ++n) acc[m][n] = (f32x4){0.f, 0.f, 0.f, 0.f};

  float4 areg[4];
  load_f32_slots(Qb, m0, 0, tid, areg);
#pragma unroll 1
  for (int ks = 0; ks < KSTEPS; ++ks) {
    const int k0 = ks * BK;
    __syncthreads();
    stage_frag_glds(pWh, BhS, rowB0, k0, tid);
    stage_frag_glds(pWl, BlS, rowB0, k0, tid);
    write_split_frag(areg, AhS, AlS, tid);
    if (ks + 1 < KSTEPS) load_f32_slots(Qb, m0, k0 + BK, tid, areg);
    __syncthreads();
    compute_step(AhS, AlS, BhS, BlS, acc, lane, wr, wc);
  }
  epilogue_f32(Sb, acc, m0, n0, lane, wr, wc);
}

// ---------------------------------------------------------------------------
// k3: row-wise softmax stats over S' rows (reduce over p, contiguous).
// One wave per row; 4 rows per block.
// ---------------------------------------------------------------------------
__global__ __launch_bounds__(256) void k3_rows(const float* __restrict__ Sp,
                                               float* __restrict__ mOut,
                                               float* __restrict__ rlOut) {
  const int row = blockIdx.x * 4 + (threadIdx.x >> 6);
  const int lane = threadIdx.x & 63;
  const float4* r = (const float4*)(Sp + (size_t)row * kT);

  float4 v[4];
#pragma unroll
  for (int i = 0; i < 4; ++i) v[i] = r[lane + i * 64];

  float m = -3.4e38f;
#pragma unroll
  for (int i = 0; i < 4; ++i)
    m = fmaxf(m, fmaxf(fmaxf(v[i].x, v[i].y), fmaxf(v[i].z, v[i].w)));
#pragma unroll
  for (int off = 32; off > 0; off >>= 1) m = fmaxf(m, __shfl_xor(m, off));

  float l = 0.f;
#pragma unroll
  for (int i = 0; i < 4; ++i) {
    l += __expf(v[i].x - m) + __expf(v[i].y - m) +
         __expf(v[i].z - m) + __expf(v[i].w - m);
  }
#pragma unroll
  for (int off = 32; off > 0; off >>= 1) l += __shfl_xor(l, off);

  if (lane == 0) {
    mOut[row] = m;
    rlOut[row] = 1.f / l;
  }
}

// ---------------------------------------------------------------------------
// k5: Ws[p][q] = split( exp(S'[q][p] - m[q]) * rl[q] )  — exp + split +
// transpose in one pass (64x64 LDS tiles).
// ---------------------------------------------------------------------------
__global__ __launch_bounds__(256) void k5_expT(const float* __restrict__ Sp,
                                               const float* __restrict__ mArr,
                                               const float* __restrict__ rlArr,
                                               u16* __restrict__ Wh,
                                               u16* __restrict__ Wl) {
  __shared__ float ts[64][65];
  const int b = blockIdx.z;
  const float* Sb = Sp + (size_t)b * kT * kT;
  const int t = threadIdx.x;
  const int i0 = blockIdx.y * 64, j0 = blockIdx.x * 64;  // i = q rows, j = p cols
  const int r = t >> 2, c0 = (t & 3) << 4;
  const float mv = mArr[(size_t)b * kT + i0 + r];
  const float rv = rlArr[(size_t)b * kT + i0 + r];
  const float4* g = (const float4*)(Sb + (size_t)(i0 + r) * 1024 + j0 + c0);
#pragma unroll
  for (int i = 0; i < 4; ++i) {
    const float4 v = g[i];
    ts[r][c0 + 4*i + 0] = __expf(v.x - mv) * rv;
    ts[r][c0 + 4*i + 1] = __expf(v.y - mv) * rv;
    ts[r][c0 + 4*i + 2] = __expf(v.z - mv) * rv;
    ts[r][c0 + 4*i + 3] = __expf(v.w - mv) * rv;
  }
  __syncthreads();
  FragU h0, l0, h1, l1;
#pragma unroll
  for (int i = 0; i < 8; ++i) {
    const float x = ts[c0 + i][r];
    const u16 h = f2bf(x); h0.u[i] = h; l0.u[i] = f2bf(x - bf2f(h));
  }
#pragma unroll
  for (int i = 0; i < 8; ++i) {
    const float x = ts[c0 + 8 + i][r];
    const u16 h = f2bf(x); h1.u[i] = h; l1.u[i] = f2bf(x - bf2f(h));
  }
  u16* dh = Wh + (size_t)b * kT * kT + (size_t)(j0 + r) * 1024 + i0 + c0;
  u16* dl = Wl + (size_t)b * kT * kT + (size_t)(j0 + r) * 1024 + i0 + c0;
  *(frag*)dh = h0.v; *((frag*)dh + 1) = h1.v;
  *(frag*)dl = l0.v; *((frag*)dl + 1) = l1.v;
}

// ---------------------------------------------------------------------------
// conv_t_split: transpose + hi/lo split (f32 -> bf16 pair). dst[j][i]=src[i][j].
// ---------------------------------------------------------------------------
__global__ __launch_bounds__(256) void conv_t_split(const float* __restrict__ src,
                                                    u16* __restrict__ dstH,
                                                    u16* __restrict__ dstL) {
  __shared__ float ts[64][65];
  const size_t boff = (size_t)blockIdx.z * kT * kD;
  const int t = threadIdx.x;
  const int i0 = blockIdx.y * 64, j0 = blockIdx.x * 64;
  const int r = t >> 2, c0 = (t & 3) << 4;
  const float4* g = (const float4*)(src + boff + (size_t)(i0 + r) * 1024 + j0 + c0);
#pragma unroll
  for (int i = 0; i < 4; ++i) {
    const float4 v = g[i];
    ts[r][c0 + 4*i + 0] = v.x; ts[r][c0 + 4*i + 1] = v.y;
    ts[r][c0 + 4*i + 2] = v.z; ts[r][c0 + 4*i + 3] = v.w;
  }
  __syncthreads();
  FragU h0, l0, h1, l1;
#pragma unroll
  for (int i = 0; i < 8; ++i) {
    const float x = ts[c0 + i][r];
    const u16 h = f2bf(x); h0.u[i] = h; l0.u[i] = f2bf(x - bf2f(h));
  }
#pragma unroll
  for (int i = 0; i < 8; ++i) {
    const float x = ts[c0 + 8 + i][r];
    const u16 h = f2bf(x); h1.u[i] = h; l1.u[i] = f2bf(x - bf2f(h));
  }
  u16* dh = dstH + boff + (size_t)(j0 + r) * 1024 + i0 + c0;
  u16* dl = dstL + boff + (size_t)(j0 + r) * 1024 + i0 + c0;
  *(frag*)dh = h0.v; *((frag*)dh + 1) = h1.v;
  *(frag*)dl = l0.v; *((frag*)dl + 1) = l1.v;
}

// ---------------------------------------------------------------------------
// g4: out[b] = Ws[b] @ qT[b]^T.  Pure glds bf16 GEMM (both operands pre-split).
// ---------------------------------------------------------------------------
__global__ __launch_bounds__(256) void g4_out(const u16* __restrict__ Wh,
                                              const u16* __restrict__ Wl,
                                              const u16* __restrict__ qTh,
                                              const u16* __restrict__ qTl,
                                              float* __restrict__ Out) {
  __shared__ __align__(16) u16 AhS[4096], AlS[4096], BhS[4096], BlS[4096];
  const int tid = threadIdx.x, lane = tid & 63;
  const int wid = tid >> 6, wr = wid >> 1, wc = wid & 1;
  const int b = blockIdx.z;
  const int m0 = blockIdx.y * BM, n0 = blockIdx.x * BN;  // m = p rows, n = d cols
  const int rowA0 = b * kT + m0;                          // Ws flat [16384][1024]
  const u16* qThb = qTh + (size_t)b * kD * kT;
  const u16* qTlb = qTl + (size_t)b * kD * kT;
  float* Ob = Out + (size_t)b * kT * kD;

  f32x4 acc[4][4];
#pragma unroll
  for (int m = 0; m < 4; ++m)
#pragma unroll
    for (int n = 0; n < 4; ++n) acc[m][n] = (f32x4){0.f, 0.f, 0.f, 0.f};

#pragma unroll 1
  for (int ks = 0; ks < KSTEPS; ++ks) {
    const int k0 = ks * BK;
    __syncthreads();
    stage_frag_glds(Wh, AhS, rowA0, k0, tid);
    stage_frag_glds(Wl, AlS, rowA0, k0, tid);
    stage_frag_glds(qThb, BhS, n0, k0, tid);
    stage_frag_glds(qTlb, BlS, n0, k0, tid);
    __syncthreads();
    compute_step(AhS, AlS, BhS, BlS, acc, lane, wr, wc);
  }
  epilogue_f32(Ob, acc, m0, n0, lane, wr, wc);
}

}  // namespace

extern "C" void kernel_launch(void* const* d_in, const int* in_sizes, int n_in,
                              void* d_out, int out_size, void* d_ws, size_t ws_size,
                              hipStream_t stream) {
  const float* q = (const float*)d_in[0];  // [B, TQ, DQ]
  const float* p = (const float*)d_in[1];  // [B, TP, DP]
  const float* W = (const float*)d_in[2];  // [DP, DQ]
  float* out = (float*)d_out;              // [B, TP, DQ]

  char* wsb = (char*)d_ws;
  u16* pWh = (u16*)wsb;                               // 32MB
  u16* pWl = (u16*)(wsb + (32ull << 20));             // 32MB
  u16* Wsh = pWh;                                     // alias (pW dead after g2')
  u16* Wsl = pWl;
  float* Sp  = (float*)(wsb + (64ull << 20));         // 64MB
  u16* WTh = (u16*)(wsb + (64ull << 20));             // 2MB, dead before Sp written
  u16* WTl = (u16*)(wsb + (64ull << 20) + (2ull << 20));
  u16* qTh = (u16*)(wsb + (64ull << 20));             // alias (S' dead after k5)
  u16* qTl = (u16*)(wsb + (96ull << 20));
  float* mArr  = (float*)(wsb + (128ull << 20));      // 64KB
  float* rlArr = mArr + (size_t)kB * kT;              // 64KB

  const dim3 blk(256);
  conv_t_split<<<dim3(16, 16, 1), blk, 0, stream>>>(W, WTh, WTl);
  g1_pw<<<dim3(kD / BN, (kB * kT) / BM), blk, 0, stream>>>(p, WTh, WTl, pWh, pWl);
  g2_scoresT<<<dim3(kT / BN, kT / BM, kB), blk, 0, stream>>>(q, pWh, pWl, Sp);
  k3_rows<<<dim3((kB * kT) / 4), blk, 0, stream>>>(Sp, mArr, rlArr);
  k5_expT<<<dim3(16, 16, kB), blk, 0, stream>>>(Sp, mArr, rlArr, Wsh, Wsl);
  conv_t_split<<<dim3(16, 16, kB), blk, 0, stream>>>(q, qTh, qTl);
  g4_out<<<dim3(kD / BN, kT / BM, kB), blk, 0, stream>>>(Wsh, Wsl, qTh, qTl, out);
}